// Round 12
// baseline (57.012 us; speedup 1.0000x reference)
//
#include <hip/hip_runtime.h>

// N=2, L=1024, C=256, H=64, E=16, CL=64, LOUT=960
// qT/kT: [n][h][l][e] fp32 ; vT: [n][h][l] fp32 ; attT: [n][h][l'] fp32

typedef __attribute__((ext_vector_type(8))) __bf16 bf16x8;
typedef __attribute__((ext_vector_type(8))) short short8;
typedef __attribute__((ext_vector_type(16))) float f32x16;

__device__ inline unsigned short bf16_rne(float x) {
    unsigned u = __builtin_bit_cast(unsigned, x);
    unsigned r = u + 0x7fffu + ((u >> 16) & 1u);
    return (unsigned short)(r >> 16);
}
__device__ inline float bf16_f(unsigned short h) {
    return __builtin_bit_cast(float, (unsigned)h << 16);
}

// ---------------------------------------------------------------------------
// Kernel 1 (v5): QKV projection, MFMA 32x32x16, split-3, WITH FUSED fp32->bf16
// hi/lo conversion (convert_split kernel eliminated -> 4 graph nodes -> 3).
// BM=64, BN=128, BK=64. 256 thr (4 waves 2m x 2n). 544 jobs. LDS 48KB, 3 blk/CU.
// Staging: global fp32 -> regs -> convert -> ds_write into the SAME
// XOR-swizzled layout as v4 (global slot s stored at pos s^(row&7); read path
// unchanged). Conversion uses the same bf16_rne as the old convert kernel ->
// bitwise-identical MFMA inputs -> absmax unchanged.
// Write-conflict audit: A-writes (16 rows x 4 slot-groups) and B-writes
// (32 rows x 2 col-groups) both tile all 32 banks per 8-lane phase group.
// LDS map (ushort): Xh@0, Xl@4096, Wh@8192, Wl@16384.
// ---------------------------------------------------------------------------
__device__ __forceinline__ bf16x8 ldsfrag2(const unsigned short* lds, int base, int row, int so) {
    return __builtin_bit_cast(bf16x8, *reinterpret_cast<const short8*>(
        lds + base + row * 64 + (((so ^ (row & 7)) & 7) << 3)));
}

__global__ __launch_bounds__(256, 3) void qkv_mfma(
    const float* __restrict__ Xf,
    const float* __restrict__ Wq, const float* __restrict__ Wk, const float* __restrict__ Wv,
    const float* __restrict__ bq, const float* __restrict__ bk, const float* __restrict__ bv,
    float* __restrict__ qT, float* __restrict__ kT, float* __restrict__ vT)
{
    __shared__ unsigned short lds[24576];   // 48 KB

    const int tid  = threadIdx.x;
    const int lane = tid & 63;
    const int wid  = tid >> 6;          // 0..3
    const int wm   = wid >> 1;          // 0..1 -> m half (32 rows)
    const int wn   = wid & 1;           // 0..1 -> n half (64 cols)

    const int job = blockIdx.x;
    int m0, o0;
    if (job < 512) { m0 = (job & 31) * 64; o0 = (job >> 5) * 128; }
    else           { m0 = (job - 512) * 64; o0 = 2048; }

    f32x16 acc[2];
    #pragma unroll
    for (int j = 0; j < 2; ++j)
        acc[j] = f32x16{0.f,0.f,0.f,0.f,0.f,0.f,0.f,0.f,0.f,0.f,0.f,0.f,0.f,0.f,0.f,0.f};

    // staging geometry: A row ra (16 cols at ca), B row rb (32 cols at cb)
    const int ra = tid >> 2, ca = (tid & 3) << 4;
    const int rb = tid >> 1, cb = (tid & 1) << 5;
    const float* arow_p = Xf + (m0 + ra) * 256;
    const int orow = o0 + rb;
    const float* brow_p;
    if (orow < 1024)      brow_p = Wq + orow * 256;
    else if (orow < 2048) brow_p = Wk + (orow - 1024) * 256;
    else                  brow_p = Wv + (min(orow, 2111) - 2048) * 256;  // clamp: rows 2112+ computed-but-never-stored

    const int arow = wm * 32 + (lane & 31);   // MFMA A row (fixed per lane)
    const int kh   = lane >> 5;               // k-half selector

    for (int k0 = 0; k0 < 256; k0 += 64) {
        // ---- load fp32 tiles to registers (issued before barrier: latency
        //      hides under prior compute / barrier wait)
        float fa[16], fb[32];
        #pragma unroll
        for (int i = 0; i < 4; ++i)
            *reinterpret_cast<float4*>(&fa[i * 4]) =
                *reinterpret_cast<const float4*>(arow_p + k0 + ca + i * 4);
        #pragma unroll
        for (int i = 0; i < 8; ++i)
            *reinterpret_cast<float4*>(&fb[i * 4]) =
                *reinterpret_cast<const float4*>(brow_p + k0 + cb + i * 4);

        __syncthreads();   // prior k-step's LDS reads complete

        // ---- convert + swizzled ds_write: A (2 slots), B (4 slots), hi+lo
        #pragma unroll
        for (int s2 = 0; s2 < 2; ++s2) {
            short8 h8, l8;
            #pragma unroll
            for (int j = 0; j < 8; ++j) {
                const float f = fa[s2 * 8 + j];
                const unsigned short hh = bf16_rne(f);
                h8[j] = (short)hh;
                l8[j] = (short)bf16_rne(f - bf16_f(hh));
            }
            const int sp = ((((ca >> 3) + s2) ^ (ra & 7)) & 7) << 3;
            *reinterpret_cast<short8*>(&lds[0    + ra * 64 + sp]) = h8;
            *reinterpret_cast<short8*>(&lds[4096 + ra * 64 + sp]) = l8;
        }
        #pragma unroll
        for (int s2 = 0; s2 < 4; ++s2) {
            short8 h8, l8;
            #pragma unroll
            for (int j = 0; j < 8; ++j) {
                const float f = fb[s2 * 8 + j];
                const unsigned short hh = bf16_rne(f);
                h8[j] = (short)hh;
                l8[j] = (short)bf16_rne(f - bf16_f(hh));
            }
            const int sp = ((((cb >> 3) + s2) ^ (rb & 7)) & 7) << 3;
            *reinterpret_cast<short8*>(&lds[8192  + rb * 64 + sp]) = h8;
            *reinterpret_cast<short8*>(&lds[16384 + rb * 64 + sp]) = l8;
        }
        __syncthreads();   // tiles ready

        // ---- compute: 24 MFMA (32x32x16) per k0 per wave
        #pragma unroll
        for (int kk = 0; kk < 64; kk += 16) {
            const int so = (kk >> 3) + kh;   // 16B slot 0..7
            bf16x8 aH = ldsfrag2(lds, 0,     arow, so);
            bf16x8 aL = ldsfrag2(lds, 4096,  arow, so);
            #pragma unroll
            for (int ot = 0; ot < 2; ++ot) {
                const int brow = wn * 64 + ot * 32 + (lane & 31);
                bf16x8 bH = ldsfrag2(lds, 8192,  brow, so);
                bf16x8 bL = ldsfrag2(lds, 16384, brow, so);
                acc[ot] = __builtin_amdgcn_mfma_f32_32x32x16_bf16(aH, bH, acc[ot], 0, 0, 0);
                acc[ot] = __builtin_amdgcn_mfma_f32_32x32x16_bf16(aH, bL, acc[ot], 0, 0, 0);
                acc[ot] = __builtin_amdgcn_mfma_f32_32x32x16_bf16(aL, bH, acc[ot], 0, 0, 0);
            }
        }
    }

    // ---- epilogue: bias + transposed scatter (32x32 C/D mapping, m74-verified)
    const int dcol = lane & 31;
    const int rbase4 = 4 * (lane >> 5);
    const int mode = (o0 < 1024) ? 0 : (o0 < 2048 ? 1 : 2);

    if (mode < 2) {
        float* __restrict__ T = mode ? kT : qT;
        const float* __restrict__ bias = mode ? bk : bq;
        const int ob = mode * 1024;
        #pragma unroll
        for (int ot = 0; ot < 2; ++ot) {
            const int o = o0 + wn * 64 + ot * 32 + dcol;
            const int h = (o >> 4) & 63;
            const int e = o & 15;
            const float bval = bias[o - ob];
            #pragma unroll
            for (int r = 0; r < 16; ++r) {
                const int mrow = (r & 3) + 8 * (r >> 2) + rbase4;
                const int m = m0 + wm * 32 + mrow;
                const int n = m >> 10, l = m & 1023;
                T[((n * 64 + h) * 1024 + l) * 16 + e] = acc[ot][r] + bval;
            }
        }
    } else if (wn == 0) {   // V: cols 2048..2111 only (first 64 of tile)
        #pragma unroll
        for (int ot = 0; ot < 2; ++ot) {
            const int hV = ot * 32 + dcol;   // 0..63
            const float bval = bv[hV];
            #pragma unroll
            for (int r = 0; r < 16; ++r) {
                const int mrow = (r & 3) + 8 * (r >> 2) + rbase4;
                const int m = m0 + wm * 32 + mrow;
                const int n = m >> 10, l = m & 1023;
                vT[(n * 64 + hV) * 1024 + l] = acc[ot][r] + bval;
            }
        }
    }
}

// ---------------------------------------------------------------------------
// Kernel 2 (v4): sliding-window attention. 256 thr (4 waves), block handles
// (n, h, 256 consecutive outputs). Lane = output position.
// K column-major float2 e-pair planes, stride 322 (2-way alias only).
// ---------------------------------------------------------------------------
__global__ __launch_bounds__(256) void attn_kernel(
    const float* __restrict__ qT, const float* __restrict__ kT,
    const float* __restrict__ vT, const float* __restrict__ PE,
    float* __restrict__ attT)
{
    __shared__ float2 kc[8 * 322];
    __shared__ float pe_lds[64 * 16];
    __shared__ float v_lds[320];

    const int tid  = threadIdx.x;
    const int lane = tid & 63;
    const int w    = tid >> 6;
    const int xb = blockIdx.x;
    const int h  = blockIdx.y;
    const int n  = blockIdx.z;
    const int l0 = xb * 256;

    const int nrows = min(319, 1024 - l0);
    const float4* kb4 = reinterpret_cast<const float4*>(kT + ((size_t)(n * 64 + h) * 1024 + l0) * 16);
    for (int u = tid; u < nrows * 4; u += 256) {
        const int row = u >> 2, f = u & 3;
        const float4 g = kb4[u];
        kc[(2 * f + 0) * 322 + row] = make_float2(g.x, g.y);
        kc[(2 * f + 1) * 322 + row] = make_float2(g.z, g.w);
    }
    {
        const int d = tid >> 2, f = tid & 3;
        *reinterpret_cast<float4*>(&pe_lds[d * 16 + f * 4]) =
            *reinterpret_cast<const float4*>(&PE[(d * 64 + h) * 16 + f * 4]);
    }
    const float* vbase = vT + (size_t)(n * 64 + h) * 1024 + l0;
    for (int u = tid; u < nrows; u += 256) v_lds[u] = vbase[u];

    const int lout = l0 + w * 64 + lane;
    const bool active = lout < 960;
    const int lq = active ? lout : 959;
    float4 q0, q1, q2, q3;
    {
        const float4* qb = reinterpret_cast<const float4*>(
            qT + ((size_t)(n * 64 + h) * 1024 + lq + 32) * 16);
        q0 = qb[0]; q1 = qb[1]; q2 = qb[2]; q3 = qb[3];
    }
    __syncthreads();

    const int rbase = w * 64 + lane;
    float den = 0.f, pv = 0.f;
    #pragma unroll 2
    for (int d = 0; d < 64; ++d) {
        const int r = rbase + d;
        const float2 c0 = kc[0 * 322 + r], c1 = kc[1 * 322 + r];
        const float2 c2 = kc[2 * 322 + r], c3 = kc[3 * 322 + r];
        const float2 c4 = kc[4 * 322 + r], c5 = kc[5 * 322 + r];
        const float2 c6 = kc[6 * 322 + r], c7 = kc[7 * 322 + r];
        const float4* pr = reinterpret_cast<const float4*>(&pe_lds[d * 16]);
        const float4 p0 = pr[0], p1 = pr[1], p2 = pr[2], p3 = pr[3];
        float s0 = (c0.x + p0.x) * q0.x + (c0.y + p0.y) * q0.y
                 + (c1.x + p0.z) * q0.z + (c1.y + p0.w) * q0.w;
        float s1 = (c2.x + p1.x) * q1.x + (c2.y + p1.y) * q1.y
                 + (c3.x + p1.z) * q1.z + (c3.y + p1.w) * q1.w;
        float s2 = (c4.x + p2.x) * q2.x + (c4.y + p2.y) * q2.y
                 + (c5.x + p2.z) * q2.z + (c5.y + p2.w) * q2.w;
        float s3 = (c6.x + p3.x) * q3.x + (c6.y + p3.y) * q3.y
                 + (c7.x + p3.z) * q3.z + (c7.y + p3.w) * q3.w;
        const float s = (s0 + s1) + (s2 + s3);
        const float p = __expf(s - 16.f);   // fixed shift: exact softmax ratio
        den += p;
        pv += p * v_lds[r];
    }
    if (active)
        attT[(size_t)(n * 64 + h) * 960 + lout] = fmaxf(pv / den, 0.f);
}

// ---------------------------------------------------------------------------
// Kernel 3 (v3): 4x FC(64->64, ReLU) + head. 512 thr, 16 rows/block, 120 blk.
// ---------------------------------------------------------------------------
__global__ __launch_bounds__(512) void fc_kernel(
    const float* __restrict__ attT,
    const float* __restrict__ fc_w, const float* __restrict__ fc_b,
    const float* __restrict__ Wout, const float* __restrict__ bout,
    float* __restrict__ out)
{
    __shared__ float w_lds[64 * 68];
    __shared__ float wo_lds[3 * 64];
    __shared__ float bufA[16 * 68];
    __shared__ float bufB[16 * 68];

    const int tid = threadIdx.x;
    const int o  = tid & 63;
    const int rr = tid >> 6;
    const int blk = blockIdx.x;
    const int n  = blk / 60;
    const int l0 = (blk - n * 60) * 16;
    const int R0 = n * 960 + l0;

    for (int idx = tid; idx < 192; idx += 512) wo_lds[idx] = Wout[idx];
    for (int idx = tid; idx < 1024; idx += 512) {
        const int hh = idx >> 4, r = idx & 15;
        bufA[r * 68 + hh] = attT[(size_t)(n * 64 + hh) * 960 + l0 + r];
    }

    float* cur = bufA;
    float* nxt = bufB;

    for (int layer = 0; layer < 4; ++layer) {
        __syncthreads();
        const float4* wsrc = reinterpret_cast<const float4*>(fc_w + layer * 4096);
        for (int u = tid; u < 1024; u += 512) {
            const int oo = u >> 4, f = u & 15;
            *reinterpret_cast<float4*>(&w_lds[oo * 68 + f * 4]) = wsrc[u];
        }
        __syncthreads();
        const float bias = fc_b[layer * 64 + o];
        const float4* wr = reinterpret_cast<const float4*>(&w_lds[o * 68]);
        #pragma unroll
        for (int rb = 0; rb < 2; ++rb) {
            const int r = rr + rb * 8;
            float acc = bias;
            const float4* cr = reinterpret_cast<const float4*>(&cur[r * 68]);
            #pragma unroll
            for (int t = 0; t < 16; ++t) {
                const float4 c = cr[t], wv = wr[t];
                acc += c.x * wv.x + c.y * wv.y + c.z * wv.z + c.w * wv.w;
            }
            nxt[r * 68 + o] = fmaxf(acc, 0.f);
        }
        float* tmp = cur; cur = nxt; nxt = tmp;
    }
    __syncthreads();

    if (o < 3) {
        #pragma unroll
        for (int rb = 0; rb < 2; ++rb) {
            const int r = rr + rb * 8;
            float acc = bout[o];
            #pragma unroll
            for (int hh = 0; hh < 64; ++hh)
                acc += cur[r * 68 + hh] * wo_lds[o * 64 + hh];
            out[(R0 + r) * 3 + o] = acc;
        }
    }
}

// ---------------------------------------------------------------------------
extern "C" void kernel_launch(void* const* d_in, const int* in_sizes, int n_in,
                              void* d_out, int out_size, void* d_ws, size_t ws_size,
                              hipStream_t stream) {
    const float* x    = (const float*)d_in[0];
    const float* Wq   = (const float*)d_in[1];
    const float* bq   = (const float*)d_in[2];
    const float* Wk   = (const float*)d_in[3];
    const float* bk   = (const float*)d_in[4];
    const float* Wv   = (const float*)d_in[5];
    const float* bv   = (const float*)d_in[6];
    const float* PE   = (const float*)d_in[7];
    const float* fc_w = (const float*)d_in[8];
    const float* fc_b = (const float*)d_in[9];
    const float* Wout = (const float*)d_in[10];
    const float* bout = (const float*)d_in[11];
    float* out = (float*)d_out;

    float* ws = (float*)d_ws;
    float* qT   = ws;                      // 2,097,152 f
    float* kT   = qT + 2097152;            // 2,097,152 f
    float* vT   = kT + 2097152;            // 131,072 f
    float* attT = vT + 131072;             // 122,880 f  [n][h][960]

    qkv_mfma<<<544, 256, 0, stream>>>(x, Wq, Wk, Wv, bq, bk, bv, qT, kT, vT);
    attn_kernel<<<dim3(4, 64, 2), 256, 0, stream>>>(qT, kT, vT, PE, attT);
    fc_kernel<<<120, 512, 0, stream>>>(attT, fc_w, fc_b, Wout, bout, out);
}

// Round 13
// 51.464 us; speedup vs baseline: 1.1078x; 1.1078x over previous
//
#include <hip/hip_runtime.h>

// N=2, L=1024, C=256, H=64, E=16, CL=64, LOUT=960
// qT/kT: [n][h][l][e] fp32 ; vT: [n][h][l] fp32 ; attT: [n][h][l'] fp32

typedef __attribute__((ext_vector_type(8))) __bf16 bf16x8;
typedef __attribute__((ext_vector_type(8))) short short8;
typedef __attribute__((ext_vector_type(4))) float f32x4;

__device__ inline unsigned short bf16_rne(float x) {
    unsigned u = __builtin_bit_cast(unsigned, x);
    unsigned r = u + 0x7fffu + ((u >> 16) & 1u);
    return (unsigned short)(r >> 16);
}
__device__ inline float bf16_f(unsigned short h) {
    return __builtin_bit_cast(float, (unsigned)h << 16);
}

// ---------------------------------------------------------------------------
// Kernel 0: split X and W=[Wq;Wk;Wv] into bf16 hi/lo planes.
// ---------------------------------------------------------------------------
__global__ __launch_bounds__(256) void convert_split(
    const float* __restrict__ X,
    const float* __restrict__ Wq, const float* __restrict__ Wk, const float* __restrict__ Wv,
    unsigned short* __restrict__ XhG, unsigned short* __restrict__ XlG,
    unsigned short* __restrict__ WhG, unsigned short* __restrict__ WlG)
{
    const int g = blockIdx.x * 256 + threadIdx.x;
    const int NX = 131072;
    const int NW = 135168;
    if (g >= NX + NW) return;

    float4 v;
    unsigned short *dh, *dl;
    int off;
    if (g < NX) {
        off = g * 4;
        v = *reinterpret_cast<const float4*>(&X[off]);
        dh = XhG; dl = XlG;
    } else {
        off = (g - NX) * 4;
        const int row = off >> 8, col = off & 255;
        const float* s;
        if (row < 1024)      s = &Wq[row * 256 + col];
        else if (row < 2048) s = &Wk[(row - 1024) * 256 + col];
        else                 s = &Wv[(row - 2048) * 256 + col];
        v = *reinterpret_cast<const float4*>(s);
        dh = WhG; dl = WlG;
    }
    unsigned short h0 = bf16_rne(v.x), h1 = bf16_rne(v.y), h2 = bf16_rne(v.z), h3 = bf16_rne(v.w);
    unsigned short l0 = bf16_rne(v.x - bf16_f(h0));
    unsigned short l1 = bf16_rne(v.y - bf16_f(h1));
    unsigned short l2 = bf16_rne(v.z - bf16_f(h2));
    unsigned short l3 = bf16_rne(v.w - bf16_f(h3));
    ushort4 hv = make_ushort4(h0, h1, h2, h3);
    ushort4 lv = make_ushort4(l0, l1, l2, l3);
    *reinterpret_cast<ushort4*>(&dh[off]) = hv;
    *reinterpret_cast<ushort4*>(&dl[off]) = lv;
}

// ---------------------------------------------------------------------------
// Kernel 1 (v3.2): QKV projection via MFMA 16x16x32, bf16 split-3.
// Exact R10 structure (53.0 us measured) + XCD-chunked job swizzle (T1):
// 544 jobs = 8 XCDs x 68 contiguous jobs -> bijective; jobs sharing a
// W-panel (32 consecutive) become XCD-local -> W/X panel L2 locality.
// BM=64, BN=128, BK=64. 256 thr (4 waves 2m x 2n). LDS 48KB -> 3 blk/CU.
// Chunk c at LDS byte c*1024 (linear gload_lds dest); pre-swizzled global
// source ss=(lane&7)^(lane>>3); XOR-swz read (rule 21).
// LDS map (ushort): Xh@0, Xl@4096, Wh@8192, Wl@16384.
// ---------------------------------------------------------------------------
__device__ __forceinline__ bf16x8 ldsfrag2(const unsigned short* lds, int base, int row, int so) {
    return __builtin_bit_cast(bf16x8, *reinterpret_cast<const short8*>(
        lds + base + row * 64 + (((so ^ (row & 7)) & 7) << 3)));
}

__global__ __launch_bounds__(256, 3) void qkv_mfma(
    const unsigned short* __restrict__ XhG, const unsigned short* __restrict__ XlG,
    const unsigned short* __restrict__ WhG, const unsigned short* __restrict__ WlG,
    const float* __restrict__ bq, const float* __restrict__ bk, const float* __restrict__ bv,
    float* __restrict__ qT, float* __restrict__ kT, float* __restrict__ vT)
{
    __shared__ unsigned short lds[24576];   // 48 KB

    const int tid  = threadIdx.x;
    const int lane = tid & 63;
    const int wid  = tid >> 6;          // 0..3
    const int wm   = wid >> 1;          // 0..1 -> m half (32 rows)
    const int wn   = wid & 1;           // 0..1 -> n half (64 cols)

    // XCD-chunked bijective swizzle: orig blockIdx -> job
    // (544 % 8 == 0 -> job = (bid & 7) * 68 + (bid >> 3))
    const int bid = blockIdx.x;
    const int job = (bid & 7) * 68 + (bid >> 3);
    int m0, o0;
    if (job < 512) { m0 = (job & 31) * 64; o0 = (job >> 5) * 128; }
    else           { m0 = (job - 512) * 64; o0 = 2048; }

    f32x4 acc[2][4];
    #pragma unroll
    for (int i = 0; i < 2; ++i)
        #pragma unroll
        for (int j = 0; j < 4; ++j)
            acc[i][j] = f32x4{0.f, 0.f, 0.f, 0.f};

    const int r8 = lane >> 3;           // row within 8-row chunk
    const int ss = (lane & 7) ^ r8;     // pre-swizzled source slot

    for (int k0 = 0; k0 < 256; k0 += 64) {
        // ---- stage 48 chunks (12 per wave) via global_load_lds width 16
        #pragma unroll
        for (int j = 0; j < 12; ++j) {
            const int c = wid * 12 + j;   // 0..47 (wave-uniform)
            const unsigned short* gsrc;
            if (c < 8)       gsrc = &XhG[(m0 + (c << 3) + r8) * 256 + k0 + (ss << 3)];
            else if (c < 16) gsrc = &XlG[(m0 + ((c - 8) << 3) + r8) * 256 + k0 + (ss << 3)];
            else if (c < 32) gsrc = &WhG[(o0 + ((c - 16) << 3) + r8) * 256 + k0 + (ss << 3)];
            else             gsrc = &WlG[(o0 + ((c - 32) << 3) + r8) * 256 + k0 + (ss << 3)];
            char* lbase = (char*)lds + (c << 10);   // uniform; HW adds lane*16
            __builtin_amdgcn_global_load_lds(
                (const __attribute__((address_space(1))) void*)gsrc,
                (__attribute__((address_space(3))) void*)lbase, 16, 0, 0);
        }
        __syncthreads();   // drains vmcnt before barrier

        // ---- compute: 48 MFMA per k0 per wave
        #pragma unroll
        for (int kk = 0; kk < 64; kk += 32) {
            const int so = (kk >> 3) + (lane >> 4);   // 16B slot 0..7
            bf16x8 aH[2], aL[2], bH[4], bL[4];
            #pragma unroll
            for (int mt = 0; mt < 2; ++mt) {
                const int ar = wm * 32 + mt * 16 + (lane & 15);
                aH[mt] = ldsfrag2(lds, 0, ar, so);
                aL[mt] = ldsfrag2(lds, 4096, ar, so);
            }
            #pragma unroll
            for (int ot = 0; ot < 4; ++ot) {
                const int br = wn * 64 + ot * 16 + (lane & 15);
                bH[ot] = ldsfrag2(lds, 8192, br, so);
                bL[ot] = ldsfrag2(lds, 16384, br, so);
            }
            #pragma unroll
            for (int mt = 0; mt < 2; ++mt)
                #pragma unroll
                for (int ot = 0; ot < 4; ++ot) {
                    acc[mt][ot] = __builtin_amdgcn_mfma_f32_16x16x32_bf16(aH[mt], bH[ot], acc[mt][ot], 0, 0, 0);
                    acc[mt][ot] = __builtin_amdgcn_mfma_f32_16x16x32_bf16(aH[mt], bL[ot], acc[mt][ot], 0, 0, 0);
                    acc[mt][ot] = __builtin_amdgcn_mfma_f32_16x16x32_bf16(aL[mt], bH[ot], acc[mt][ot], 0, 0, 0);
                }
        }
        __syncthreads();   // protect LDS before next stage
    }

    // ---- epilogue: bias + transposed scatter
    const int drow = (lane >> 4) * 4;
    const int dcol = lane & 15;
    const int mode = (o0 < 1024) ? 0 : (o0 < 2048 ? 1 : 2);

    if (mode < 2) {
        float* __restrict__ T = mode ? kT : qT;
        const float* __restrict__ bias = mode ? bk : bq;
        const int ob = mode * 1024;
        #pragma unroll
        for (int ot = 0; ot < 4; ++ot) {
            const int o = o0 + wn * 64 + ot * 16 + dcol;
            const int h = (o >> 4) & 63;
            const int e = o & 15;
            const float bval = bias[o - ob];
            #pragma unroll
            for (int mt = 0; mt < 2; ++mt)
                #pragma unroll
                for (int r = 0; r < 4; ++r) {
                    const int m = m0 + wm * 32 + mt * 16 + drow + r;
                    const int n = m >> 10, l = m & 1023;
                    T[((n * 64 + h) * 1024 + l) * 16 + e] = acc[mt][ot][r] + bval;
                }
        }
    } else if (wn == 0) {   // V: cols 2048..2111 only (first 64 of tile)
        #pragma unroll
        for (int ot = 0; ot < 4; ++ot) {
            const int hV = ot * 16 + dcol;   // 0..63
            const float bval = bv[hV];
            #pragma unroll
            for (int mt = 0; mt < 2; ++mt)
                #pragma unroll
                for (int r = 0; r < 4; ++r) {
                    const int m = m0 + wm * 32 + mt * 16 + drow + r;
                    const int n = m >> 10, l = m & 1023;
                    vT[(n * 64 + hV) * 1024 + l] = acc[mt][ot][r] + bval;
                }
        }
    }
}

// ---------------------------------------------------------------------------
// Kernel 2 (v4): sliding-window attention. 256 thr (4 waves), block handles
// (n, h, 256 consecutive outputs). Lane = output position.
// K column-major float2 e-pair planes, stride 322 (2-way alias only).
// ---------------------------------------------------------------------------
__global__ __launch_bounds__(256) void attn_kernel(
    const float* __restrict__ qT, const float* __restrict__ kT,
    const float* __restrict__ vT, const float* __restrict__ PE,
    float* __restrict__ attT)
{
    __shared__ float2 kc[8 * 322];
    __shared__ float pe_lds[64 * 16];
    __shared__ float v_lds[320];

    const int tid  = threadIdx.x;
    const int lane = tid & 63;
    const int w    = tid >> 6;
    const int xb = blockIdx.x;
    const int h  = blockIdx.y;
    const int n  = blockIdx.z;
    const int l0 = xb * 256;

    const int nrows = min(319, 1024 - l0);
    const float4* kb4 = reinterpret_cast<const float4*>(kT + ((size_t)(n * 64 + h) * 1024 + l0) * 16);
    for (int u = tid; u < nrows * 4; u += 256) {
        const int row = u >> 2, f = u & 3;
        const float4 g = kb4[u];
        kc[(2 * f + 0) * 322 + row] = make_float2(g.x, g.y);
        kc[(2 * f + 1) * 322 + row] = make_float2(g.z, g.w);
    }
    {
        const int d = tid >> 2, f = tid & 3;
        *reinterpret_cast<float4*>(&pe_lds[d * 16 + f * 4]) =
            *reinterpret_cast<const float4*>(&PE[(d * 64 + h) * 16 + f * 4]);
    }
    const float* vbase = vT + (size_t)(n * 64 + h) * 1024 + l0;
    for (int u = tid; u < nrows; u += 256) v_lds[u] = vbase[u];

    const int lout = l0 + w * 64 + lane;
    const bool active = lout < 960;
    const int lq = active ? lout : 959;
    float4 q0, q1, q2, q3;
    {
        const float4* qb = reinterpret_cast<const float4*>(
            qT + ((size_t)(n * 64 + h) * 1024 + lq + 32) * 16);
        q0 = qb[0]; q1 = qb[1]; q2 = qb[2]; q3 = qb[3];
    }
    __syncthreads();

    const int rbase = w * 64 + lane;
    float den = 0.f, pv = 0.f;
    #pragma unroll 2
    for (int d = 0; d < 64; ++d) {
        const int r = rbase + d;
        const float2 c0 = kc[0 * 322 + r], c1 = kc[1 * 322 + r];
        const float2 c2 = kc[2 * 322 + r], c3 = kc[3 * 322 + r];
        const float2 c4 = kc[4 * 322 + r], c5 = kc[5 * 322 + r];
        const float2 c6 = kc[6 * 322 + r], c7 = kc[7 * 322 + r];
        const float4* pr = reinterpret_cast<const float4*>(&pe_lds[d * 16]);
        const float4 p0 = pr[0], p1 = pr[1], p2 = pr[2], p3 = pr[3];
        float s0 = (c0.x + p0.x) * q0.x + (c0.y + p0.y) * q0.y
                 + (c1.x + p0.z) * q0.z + (c1.y + p0.w) * q0.w;
        float s1 = (c2.x + p1.x) * q1.x + (c2.y + p1.y) * q1.y
                 + (c3.x + p1.z) * q1.z + (c3.y + p1.w) * q1.w;
        float s2 = (c4.x + p2.x) * q2.x + (c4.y + p2.y) * q2.y
                 + (c5.x + p2.z) * q2.z + (c5.y + p2.w) * q2.w;
        float s3 = (c6.x + p3.x) * q3.x + (c6.y + p3.y) * q3.y
                 + (c7.x + p3.z) * q3.z + (c7.y + p3.w) * q3.w;
        const float s = (s0 + s1) + (s2 + s3);
        const float p = __expf(s - 16.f);   // fixed shift: exact softmax ratio
        den += p;
        pv += p * v_lds[r];
    }
    if (active)
        attT[(size_t)(n * 64 + h) * 960 + lout] = fmaxf(pv / den, 0.f);
}

// ---------------------------------------------------------------------------
// Kernel 3 (v3): 4x FC(64->64, ReLU) + head. 512 thr, 16 rows/block, 120 blk.
// ---------------------------------------------------------------------------
__global__ __launch_bounds__(512) void fc_kernel(
    const float* __restrict__ attT,
    const float* __restrict__ fc_w, const float* __restrict__ fc_b,
    const float* __restrict__ Wout, const float* __restrict__ bout,
    float* __restrict__ out)
{
    __shared__ float w_lds[64 * 68];
    __shared__ float wo_lds[3 * 64];
    __shared__ float bufA[16 * 68];
    __shared__ float bufB[16 * 68];

    const int tid = threadIdx.x;
    const int o  = tid & 63;
    const int rr = tid >> 6;
    const int blk = blockIdx.x;
    const int n  = blk / 60;
    const int l0 = (blk - n * 60) * 16;
    const int R0 = n * 960 + l0;

    for (int idx = tid; idx < 192; idx += 512) wo_lds[idx] = Wout[idx];
    for (int idx = tid; idx < 1024; idx += 512) {
        const int hh = idx >> 4, r = idx & 15;
        bufA[r * 68 + hh] = attT[(size_t)(n * 64 + hh) * 960 + l0 + r];
    }

    float* cur = bufA;
    float* nxt = bufB;

    for (int layer = 0; layer < 4; ++layer) {
        __syncthreads();
        const float4* wsrc = reinterpret_cast<const float4*>(fc_w + layer * 4096);
        for (int u = tid; u < 1024; u += 512) {
            const int oo = u >> 4, f = u & 15;
            *reinterpret_cast<float4*>(&w_lds[oo * 68 + f * 4]) = wsrc[u];
        }
        __syncthreads();
        const float bias = fc_b[layer * 64 + o];
        const float4* wr = reinterpret_cast<const float4*>(&w_lds[o * 68]);
        #pragma unroll
        for (int rb = 0; rb < 2; ++rb) {
            const int r = rr + rb * 8;
            float acc = bias;
            const float4* cr = reinterpret_cast<const float4*>(&cur[r * 68]);
            #pragma unroll
            for (int t = 0; t < 16; ++t) {
                const float4 c = cr[t], wv = wr[t];
                acc += c.x * wv.x + c.y * wv.y + c.z * wv.z + c.w * wv.w;
            }
            nxt[r * 68 + o] = fmaxf(acc, 0.f);
        }
        float* tmp = cur; cur = nxt; nxt = tmp;
    }
    __syncthreads();

    if (o < 3) {
        #pragma unroll
        for (int rb = 0; rb < 2; ++rb) {
            const int r = rr + rb * 8;
            float acc = bout[o];
            #pragma unroll
            for (int hh = 0; hh < 64; ++hh)
                acc += cur[r * 68 + hh] * wo_lds[o * 64 + hh];
            out[(R0 + r) * 3 + o] = acc;
        }
    }
}

// ---------------------------------------------------------------------------
extern "C" void kernel_launch(void* const* d_in, const int* in_sizes, int n_in,
                              void* d_out, int out_size, void* d_ws, size_t ws_size,
                              hipStream_t stream) {
    const float* x    = (const float*)d_in[0];
    const float* Wq   = (const float*)d_in[1];
    const float* bq   = (const float*)d_in[2];
    const float* Wk   = (const float*)d_in[3];
    const float* bk   = (const float*)d_in[4];
    const float* Wv   = (const float*)d_in[5];
    const float* bv   = (const float*)d_in[6];
    const float* PE   = (const float*)d_in[7];
    const float* fc_w = (const float*)d_in[8];
    const float* fc_b = (const float*)d_in[9];
    const float* Wout = (const float*)d_in[10];
    const float* bout = (const float*)d_in[11];
    float* out = (float*)d_out;

    float* ws = (float*)d_ws;
    float* qT   = ws;                      // 2,097,152 f
    float* kT   = qT + 2097152;            // 2,097,152 f
    float* vT   = kT + 2097152;            // 131,072 f
    float* attT = vT + 131072;             // 122,880 f  [n][h][960]
    unsigned short* XhG = (unsigned short*)(attT + 122880);
    unsigned short* XlG = XhG + 524288;
    unsigned short* WhG = XlG + 524288;
    unsigned short* WlG = WhG + 540672;

    convert_split<<<1040, 256, 0, stream>>>(x, Wq, Wk, Wv, XhG, XlG, WhG, WlG);
    qkv_mfma<<<544, 256, 0, stream>>>(XhG, XlG, WhG, WlG, bq, bk, bv, qT, kT, vT);
    attn_kernel<<<dim3(4, 64, 2), 256, 0, stream>>>(qT, kT, vT, PE, attT);
    fc_kernel<<<120, 512, 0, stream>>>(attT, fc_w, fc_b, Wout, bout, out);
}